// Round 1
// baseline (830.852 us; speedup 1.0000x reference)
//
#include <hip/hip_runtime.h>
#include <cstdint>
#include <cstddef>

#define DEVI __device__ __forceinline__

typedef __attribute__((ext_vector_type(8))) short bf16x8;
typedef __attribute__((ext_vector_type(4))) float f32x4;

DEVI unsigned short f2bf(float f) {
  unsigned int u = __float_as_uint(f);
  u += 0x7fffu + ((u >> 16) & 1u);   // RNE
  return (unsigned short)(u >> 16);
}
DEVI float bf2f(unsigned int us) { return __uint_as_float(us << 16); }

DEVI void gld_lds16(const void* g, void* l) {
  __builtin_amdgcn_global_load_lds(
      (const __attribute__((address_space(1))) void*)g,
      (__attribute__((address_space(3))) void*)l, 16, 0, 0);
}

// ---------------- fp32 -> bf16 elementwise ----------------
__global__ __launch_bounds__(256) void k_conv(const float* __restrict__ in,
                                              short* __restrict__ out, int n4) {
  int i = blockIdx.x * 256 + threadIdx.x;
  if (i >= n4) return;
  float4 v = reinterpret_cast<const float4*>(in)[i];
  uint2 o;
  o.x = (unsigned)f2bf(v.x) | ((unsigned)f2bf(v.y) << 16);
  o.y = (unsigned)f2bf(v.z) | ((unsigned)f2bf(v.w) << 16);
  reinterpret_cast<uint2*>(out)[i] = o;
}

// ---------------- fp32 [R][C] -> bf16 [C][R] transpose ----------------
__global__ __launch_bounds__(256) void k_transpose(const float* __restrict__ in,
                                                   short* __restrict__ out,
                                                   int R, int Cc) {
  __shared__ short tile[64][66];
  int tcols = Cc >> 6;
  int tb = blockIdx.x % tcols;
  int rb = blockIdx.x / tcols;
  int tid = threadIdx.x;
#pragma unroll
  for (int rep = 0; rep < 16; ++rep) {
    int idx = rep * 256 + tid;
    int r = idx >> 6, c = idx & 63;
    tile[r][c] = (short)f2bf(in[(size_t)(rb * 64 + r) * Cc + tb * 64 + c]);
  }
  __syncthreads();
#pragma unroll
  for (int rep = 0; rep < 16; ++rep) {
    int idx = rep * 256 + tid;
    int r = idx >> 6, c = idx & 63;
    out[(size_t)(tb * 64 + r) * R + rb * 64 + c] = tile[c][r];
  }
}

// ---------------- bf16 GEMM, B^T input (m97 structure) ----------------
// C[M][N] = A[M][K] * BT[N][K]^T ; 128x128 tile, BK=64, 4 waves.
template <typename OutT>
__global__ __launch_bounds__(256) void k_gemm_bt(const short* __restrict__ A,
                                                 const short* __restrict__ BT,
                                                 OutT* __restrict__ C,
                                                 int M, int N, int K) {
  __shared__ short sA[128 * 64];
  __shared__ short sB[128 * 64];
  const int tid = threadIdx.x;
  const int wv = tid >> 6, lane = tid & 63;
  const int wr = wv >> 1, wc = wv & 1;
  const int bm = blockIdx.x * 128, bn = blockIdx.y * 128;
  const int l8r = lane >> 3, l8c = lane & 7;
  const int l16 = lane & 15, lhi = lane >> 4;

  f32x4 acc[4][4] = {};

  for (int kt = 0; kt < K; kt += 64) {
#pragma unroll
    for (int rr = 0; rr < 4; ++rr) {
      int ch = rr * 4 + wv;
      int row = ch * 8 + l8r;               // 1024B chunk = 8 rows of 128B
      gld_lds16(A + (size_t)(bm + row) * K + kt + l8c * 8, &sA[ch * 512]);
      gld_lds16(BT + (size_t)(bn + row) * K + kt + l8c * 8, &sB[ch * 512]);
    }
    __syncthreads();   // drains vmcnt(0) before barrier -> staging visible
#pragma unroll
    for (int kk = 0; kk < 64; kk += 32) {
      const int ko = kk + lhi * 8;
      bf16x8 af[4], bfr[4];
#pragma unroll
      for (int m = 0; m < 4; ++m)
        af[m] = *(const bf16x8*)&sA[(wr * 64 + m * 16 + l16) * 64 + ko];
#pragma unroll
      for (int n = 0; n < 4; ++n)
        bfr[n] = *(const bf16x8*)&sB[(wc * 64 + n * 16 + l16) * 64 + ko];
#pragma unroll
      for (int m = 0; m < 4; ++m)
#pragma unroll
        for (int n = 0; n < 4; ++n)
          acc[m][n] = __builtin_amdgcn_mfma_f32_16x16x32_bf16(af[m], bfr[n],
                                                              acc[m][n], 0, 0, 0);
    }
    __syncthreads();
  }
#pragma unroll
  for (int m = 0; m < 4; ++m) {
#pragma unroll
    for (int n = 0; n < 4; ++n) {
      int col = bn + wc * 64 + n * 16 + l16;
#pragma unroll
      for (int r = 0; r < 4; ++r) {
        int row = bm + wr * 64 + m * 16 + lhi * 4 + r;
        if constexpr (sizeof(OutT) == 2)
          C[(size_t)row * N + col] = (OutT)f2bf(acc[m][n][r]);
        else
          C[(size_t)row * N + col] = acc[m][n][r];
      }
    }
  }
}

// ---------------- RoPE: qkv -> Qr,Kr in [B,H,T,128] bf16 ----------------
__global__ __launch_bounds__(256) void k_rope(const short* __restrict__ qkv,
                                              const float* __restrict__ cosb,
                                              const float* __restrict__ sinb,
                                              short* __restrict__ Qr,
                                              short* __restrict__ Kr) {
  int gid = blockIdx.x * 4 + (threadIdx.x >> 6);  // (b*T+t)*H + h
  int lane = threadIdx.x & 63;                    // pair index 0..63
  int h = gid & 15;
  int bt = gid >> 4;
  int t = bt & 2047;
  int b = bt >> 11;
  float c = cosb[t * 64 + lane];
  float s = sinb[t * 64 + lane];
  size_t qidx = (size_t)bt * 6144 + h * 128 + 2 * lane;
  size_t oidx = ((size_t)(b * 16 + h) * 2048 + t) * 128 + 2 * lane;
  unsigned int qp = *reinterpret_cast<const unsigned int*>(qkv + qidx);
  {
    float x1 = bf2f(qp & 0xffffu), x2 = bf2f(qp >> 16);
    unsigned int o = (unsigned)f2bf(x1 * c - x2 * s) |
                     ((unsigned)f2bf(x1 * s + x2 * c) << 16);
    *reinterpret_cast<unsigned int*>(Qr + oidx) = o;
  }
  unsigned int kp = *reinterpret_cast<const unsigned int*>(qkv + qidx + 2048);
  {
    float x1 = bf2f(kp & 0xffffu), x2 = bf2f(kp >> 16);
    unsigned int o = (unsigned)f2bf(x1 * c - x2 * s) |
                     ((unsigned)f2bf(x1 * s + x2 * c) << 16);
    *reinterpret_cast<unsigned int*>(Kr + oidx) = o;
  }
}

// ---------------- V transpose: qkv v-part -> VT [B,H,128,T] bf16 ----------------
__global__ __launch_bounds__(256) void k_vtrans(const short* __restrict__ qkv,
                                                short* __restrict__ VT) {
  __shared__ short tile[64][66];
  int bh = blockIdx.x;
  int t0 = blockIdx.y * 64;
  int d0 = blockIdx.z * 64;
  int b = bh >> 4, h = bh & 15;
  int tid = threadIdx.x;
#pragma unroll
  for (int rep = 0; rep < 16; ++rep) {
    int idx = rep * 256 + tid;
    int r = idx >> 6, c = idx & 63;
    tile[r][c] = qkv[(size_t)(b * 2048 + t0 + r) * 6144 + 4096 + h * 128 + d0 + c];
  }
  __syncthreads();
#pragma unroll
  for (int rep = 0; rep < 16; ++rep) {
    int idx = rep * 256 + tid;
    int r = idx >> 6, c = idx & 63;
    VT[(size_t)(bh * 128 + d0 + r) * 2048 + t0 + c] = tile[c][r];
  }
}

// ---------------- causal flash attention ----------------
// block = (b,h,q-tile of 64). 4 waves x 16 q-rows. KVBLK=64.
// K tile LDS [64][128], VT tile LDS [128][64], both XOR-swizzled
// (linear global_load_lds dest + inverse-swizzled global source).
__global__ __launch_bounds__(256) void k_attn(const short* __restrict__ Qr,
                                              const short* __restrict__ Kr,
                                              const short* __restrict__ VT,
                                              short* __restrict__ Y) {
  __shared__ short sK[64 * 128];
  __shared__ short sVT[128 * 64];
  __shared__ short sP[4][16 * 64];
  const int tid = threadIdx.x, wv = tid >> 6, lane = tid & 63;
  const int l8r = lane >> 3, l8c = lane & 7, l16 = lane & 15, lhi = lane >> 4;
  const int bid = blockIdx.x;
  const int qt = bid & 31, bh = bid >> 5;
  const int q0 = qt * 64;
  const size_t base = (size_t)bh * 2048 * 128;

  bf16x8 qf[4];
  const int qrow = q0 + wv * 16 + l16;
#pragma unroll
  for (int ks = 0; ks < 4; ++ks)
    qf[ks] = *reinterpret_cast<const bf16x8*>(Qr + base + (size_t)qrow * 128 +
                                              ks * 32 + lhi * 8);

  f32x4 acc_o[8] = {};
  float m_run[4], l_run[4];
#pragma unroll
  for (int r = 0; r < 4; ++r) { m_run[r] = -1e30f; l_run[r] = 0.f; }
  const float kC = 0.08838834764831845f * 1.44269504088896340f; // scale*log2(e)

  for (int kv0 = 0; kv0 <= q0; kv0 += 64) {
#pragma unroll
    for (int rr = 0; rr < 4; ++rr) {
      int ch = rr * 4 + wv;
      {                                    // sK: row stride 256B, chunk = 4 rows
        int row = ch * 4 + lhi;
        int wch = l16 ^ (row & 7);         // inverse-swizzled source chunk
        gld_lds16(Kr + base + (size_t)(kv0 + row) * 128 + wch * 8, &sK[ch * 512]);
      }
      {                                    // sVT: row stride 128B, chunk = 8 rows
        int drow = ch * 8 + l8r;
        int wch = l8c ^ (drow & 7);
        gld_lds16(VT + base + (size_t)drow * 2048 + kv0 + wch * 8, &sVT[ch * 512]);
      }
    }
    __syncthreads();

    // S = Q K^T  (16 q-rows x 64 kv-cols per wave)
    f32x4 sacc[4] = {};
#pragma unroll
    for (int cf = 0; cf < 4; ++cf) {
      int krow = cf * 16 + l16;
#pragma unroll
      for (int ks = 0; ks < 4; ++ks) {
        int e = krow * 128 + ks * 32 + lhi * 8;
        bf16x8 kf = *reinterpret_cast<const bf16x8*>(&sK[e ^ ((krow & 7) << 3)]);
        sacc[cf] = __builtin_amdgcn_mfma_f32_16x16x32_bf16(qf[ks], kf, sacc[cf],
                                                           0, 0, 0);
      }
    }

    if (kv0 == q0) {                       // causal mask on diagonal tile
#pragma unroll
      for (int cf = 0; cf < 4; ++cf) {
        int col = cf * 16 + l16;
#pragma unroll
        for (int r = 0; r < 4; ++r) {
          int rowl = wv * 16 + lhi * 4 + r;
          if (col > rowl) sacc[cf][r] = -3e38f;
        }
      }
    }

    // online softmax (rows live in 16-lane groups; butterfly reductions)
    float resc[4];
#pragma unroll
    for (int r = 0; r < 4; ++r) {
      float mx = fmaxf(fmaxf(sacc[0][r], sacc[1][r]), fmaxf(sacc[2][r], sacc[3][r]));
      mx = fmaxf(mx, __shfl_xor(mx, 1));
      mx = fmaxf(mx, __shfl_xor(mx, 2));
      mx = fmaxf(mx, __shfl_xor(mx, 4));
      mx = fmaxf(mx, __shfl_xor(mx, 8));
      float mnew = fmaxf(m_run[r], mx);
      resc[r] = exp2f((m_run[r] - mnew) * kC);
      m_run[r] = mnew;
    }
    float rsum[4] = {0.f, 0.f, 0.f, 0.f};
#pragma unroll
    for (int cf = 0; cf < 4; ++cf) {
#pragma unroll
      for (int r = 0; r < 4; ++r) {
        float p = exp2f((sacc[cf][r] - m_run[r]) * kC);
        sacc[cf][r] = p;
        rsum[r] += p;
      }
    }
#pragma unroll
    for (int r = 0; r < 4; ++r) {
      float s = rsum[r];
      s += __shfl_xor(s, 1);
      s += __shfl_xor(s, 2);
      s += __shfl_xor(s, 4);
      s += __shfl_xor(s, 8);
      l_run[r] = l_run[r] * resc[r] + s;
    }
    // P -> per-wave LDS (swizzled), reshaping S-layout -> A-fragment layout
#pragma unroll
    for (int cf = 0; cf < 4; ++cf)
#pragma unroll
      for (int r = 0; r < 4; ++r) {
        int prow = lhi * 4 + r;
        int e = prow * 64 + cf * 16 + l16;
        sP[wv][e ^ ((prow & 7) << 3)] = (short)f2bf(sacc[cf][r]);
      }
#pragma unroll
    for (int df = 0; df < 8; ++df)
#pragma unroll
      for (int r = 0; r < 4; ++r) acc_o[df][r] *= resc[r];
    // O += P V
#pragma unroll
    for (int kk = 0; kk < 2; ++kk) {
      int e = l16 * 64 + kk * 32 + lhi * 8;
      bf16x8 pa = *reinterpret_cast<const bf16x8*>(&sP[wv][e ^ ((l16 & 7) << 3)]);
#pragma unroll
      for (int df = 0; df < 8; ++df) {
        int vrow = df * 16 + l16;
        int ev = vrow * 64 + kk * 32 + lhi * 8;
        bf16x8 vb = *reinterpret_cast<const bf16x8*>(&sVT[ev ^ ((vrow & 7) << 3)]);
        acc_o[df] = __builtin_amdgcn_mfma_f32_16x16x32_bf16(pa, vb, acc_o[df],
                                                            0, 0, 0);
      }
    }
    __syncthreads();
  }

  const int b = bh >> 4, h = bh & 15;
#pragma unroll
  for (int r = 0; r < 4; ++r) l_run[r] = 1.f / l_run[r];
#pragma unroll
  for (int df = 0; df < 8; ++df) {
    int col = h * 128 + df * 16 + l16;
#pragma unroll
    for (int r = 0; r < 4; ++r) {
      int row = q0 + wv * 16 + lhi * 4 + r;
      Y[((size_t)b * 2048 + row) * 2048 + col] = (short)f2bf(acc_o[df][r] * l_run[r]);
    }
  }
}

// ---------------- launch ----------------
extern "C" void kernel_launch(void* const* d_in, const int* in_sizes, int n_in,
                              void* d_out, int out_size, void* d_ws, size_t ws_size,
                              hipStream_t stream) {
  const float* x        = (const float*)d_in[0];
  const float* w_attn   = (const float*)d_in[1];
  const float* w_proj   = (const float*)d_in[2];
  const float* rope_cos = (const float*)d_in[3];
  const float* rope_sin = (const float*)d_in[4];

  char* ws = (char*)d_ws;                     // 256 MiB total layout
  short* xbf    = (short*)(ws);               // 33.5 MB  [8192][2048]
  short* wattnT = (short*)(ws + 33554432ull); // 25.2 MB  [6144][2048]
  short* wprojT = (short*)(ws + 58720256ull); //  8.4 MB  [2048][2048]
  short* qkv    = (short*)(ws + 67108864ull); // 100.7 MB [8192][6144]
  short* Y      = qkv;                        // alias dead q-region (33.5 MB)
  short* Qr     = (short*)(ws + 167772160ull);// 33.5 MB  [B,H,T,128]
  short* Kr     = (short*)(ws + 201326592ull);// 33.5 MB  [B,H,T,128]
  short* VT     = (short*)(ws + 234881024ull);// 33.5 MB  [B,H,128,T]

  k_conv<<<16384, 256, 0, stream>>>(x, xbf, 4194304);
  k_transpose<<<3072, 256, 0, stream>>>(w_attn, wattnT, 2048, 6144);
  k_transpose<<<1024, 256, 0, stream>>>(w_proj, wprojT, 2048, 2048);
  k_gemm_bt<short><<<dim3(64, 48), 256, 0, stream>>>(xbf, wattnT, qkv,
                                                     8192, 6144, 2048);
  k_rope<<<32768, 256, 0, stream>>>(qkv, rope_cos, rope_sin, Qr, Kr);
  k_vtrans<<<dim3(64, 32, 2), 256, 0, stream>>>(qkv, VT);
  k_attn<<<2048, 256, 0, stream>>>(Qr, Kr, VT, Y);
  k_gemm_bt<float><<<dim3(64, 16), 256, 0, stream>>>(Y, wprojT, (float*)d_out,
                                                     8192, 2048, 2048);
}

// Round 2
// 642.805 us; speedup vs baseline: 1.2925x; 1.2925x over previous
//
#include <hip/hip_runtime.h>
#include <cstdint>
#include <cstddef>

#define DEVI __device__ __forceinline__

typedef __attribute__((ext_vector_type(8))) short bf16x8;
typedef __attribute__((ext_vector_type(4))) float f32x4;

DEVI unsigned short f2bf(float f) {
  unsigned int u = __float_as_uint(f);
  u += 0x7fffu + ((u >> 16) & 1u);   // RNE
  return (unsigned short)(u >> 16);
}
DEVI float bf2f(unsigned int us) { return __uint_as_float(us << 16); }

DEVI void gld_lds16(const void* g, void* l) {
  __builtin_amdgcn_global_load_lds(
      (const __attribute__((address_space(1))) void*)g,
      (__attribute__((address_space(3))) void*)l, 16, 0, 0);
}

// ---------------- fp32 -> bf16 elementwise ----------------
__global__ __launch_bounds__(256) void k_conv(const float* __restrict__ in,
                                              short* __restrict__ out, int n4) {
  int i = blockIdx.x * 256 + threadIdx.x;
  if (i >= n4) return;
  float4 v = reinterpret_cast<const float4*>(in)[i];
  uint2 o;
  o.x = (unsigned)f2bf(v.x) | ((unsigned)f2bf(v.y) << 16);
  o.y = (unsigned)f2bf(v.z) | ((unsigned)f2bf(v.w) << 16);
  reinterpret_cast<uint2*>(out)[i] = o;
}

// ---------------- fp32 [R][C] -> bf16 [C][R] transpose ----------------
__global__ __launch_bounds__(256) void k_transpose(const float* __restrict__ in,
                                                   short* __restrict__ out,
                                                   int R, int Cc) {
  __shared__ short tile[64][66];
  int tcols = Cc >> 6;
  int tb = blockIdx.x % tcols;
  int rb = blockIdx.x / tcols;
  int tid = threadIdx.x;
#pragma unroll
  for (int rep = 0; rep < 16; ++rep) {
    int idx = rep * 256 + tid;
    int r = idx >> 6, c = idx & 63;
    tile[r][c] = (short)f2bf(in[(size_t)(rb * 64 + r) * Cc + tb * 64 + c]);
  }
  __syncthreads();
#pragma unroll
  for (int rep = 0; rep < 16; ++rep) {
    int idx = rep * 256 + tid;
    int r = idx >> 6, c = idx & 63;
    out[(size_t)(tb * 64 + r) * R + rb * 64 + c] = tile[c][r];
  }
}

// ---------------- bf16 GEMM, B^T input (m97 structure) ----------------
// C[M][N] = A[M][K] * BT[N][K]^T ; 128x128 tile, BK=64, 4 waves.
template <typename OutT>
__global__ __launch_bounds__(256) void k_gemm_bt(const short* __restrict__ A,
                                                 const short* __restrict__ BT,
                                                 OutT* __restrict__ C,
                                                 int M, int N, int K) {
  __shared__ short sA[128 * 64];
  __shared__ short sB[128 * 64];
  const int tid = threadIdx.x;
  const int wv = tid >> 6, lane = tid & 63;
  const int wr = wv >> 1, wc = wv & 1;
  const int bm = blockIdx.x * 128, bn = blockIdx.y * 128;
  const int l8r = lane >> 3, l8c = lane & 7;
  const int l16 = lane & 15, lhi = lane >> 4;

  f32x4 acc[4][4] = {};

  for (int kt = 0; kt < K; kt += 64) {
#pragma unroll
    for (int rr = 0; rr < 4; ++rr) {
      int ch = rr * 4 + wv;
      int row = ch * 8 + l8r;               // 1024B chunk = 8 rows of 128B
      gld_lds16(A + (size_t)(bm + row) * K + kt + l8c * 8, &sA[ch * 512]);
      gld_lds16(BT + (size_t)(bn + row) * K + kt + l8c * 8, &sB[ch * 512]);
    }
    __syncthreads();   // drains vmcnt(0) before barrier -> staging visible
#pragma unroll
    for (int kk = 0; kk < 64; kk += 32) {
      const int ko = kk + lhi * 8;
      bf16x8 af[4], bfr[4];
#pragma unroll
      for (int m = 0; m < 4; ++m)
        af[m] = *(const bf16x8*)&sA[(wr * 64 + m * 16 + l16) * 64 + ko];
#pragma unroll
      for (int n = 0; n < 4; ++n)
        bfr[n] = *(const bf16x8*)&sB[(wc * 64 + n * 16 + l16) * 64 + ko];
#pragma unroll
      for (int m = 0; m < 4; ++m)
#pragma unroll
        for (int n = 0; n < 4; ++n)
          acc[m][n] = __builtin_amdgcn_mfma_f32_16x16x32_bf16(af[m], bfr[n],
                                                              acc[m][n], 0, 0, 0);
    }
    __syncthreads();
  }
#pragma unroll
  for (int m = 0; m < 4; ++m) {
#pragma unroll
    for (int n = 0; n < 4; ++n) {
      int col = bn + wc * 64 + n * 16 + l16;
#pragma unroll
      for (int r = 0; r < 4; ++r) {
        int row = bm + wr * 64 + m * 16 + lhi * 4 + r;
        if constexpr (sizeof(OutT) == 2)
          C[(size_t)row * N + col] = (OutT)f2bf(acc[m][n][r]);
        else
          C[(size_t)row * N + col] = acc[m][n][r];
      }
    }
  }
}

// ---------------- RoPE: qkv -> Qr,Kr in [B,H,T,128] bf16 ----------------
// Q additionally pre-scaled by 1/sqrt(hd) * log2(e) so QK^T lands in exp2 domain.
__global__ __launch_bounds__(256) void k_rope(const short* __restrict__ qkv,
                                              const float* __restrict__ cosb,
                                              const float* __restrict__ sinb,
                                              short* __restrict__ Qr,
                                              short* __restrict__ Kr) {
  const float kC = 0.08838834764831845f * 1.44269504088896340f;
  int gid = blockIdx.x * 4 + (threadIdx.x >> 6);  // (b*T+t)*H + h
  int lane = threadIdx.x & 63;                    // pair index 0..63
  int h = gid & 15;
  int bt = gid >> 4;
  int t = bt & 2047;
  int b = bt >> 11;
  float c = cosb[t * 64 + lane];
  float s = sinb[t * 64 + lane];
  size_t qidx = (size_t)bt * 6144 + h * 128 + 2 * lane;
  size_t oidx = ((size_t)(b * 16 + h) * 2048 + t) * 128 + 2 * lane;
  unsigned int qp = *reinterpret_cast<const unsigned int*>(qkv + qidx);
  {
    float x1 = bf2f(qp & 0xffffu), x2 = bf2f(qp >> 16);
    unsigned int o = (unsigned)f2bf((x1 * c - x2 * s) * kC) |
                     ((unsigned)f2bf((x1 * s + x2 * c) * kC) << 16);
    *reinterpret_cast<unsigned int*>(Qr + oidx) = o;
  }
  unsigned int kp = *reinterpret_cast<const unsigned int*>(qkv + qidx + 2048);
  {
    float x1 = bf2f(kp & 0xffffu), x2 = bf2f(kp >> 16);
    unsigned int o = (unsigned)f2bf(x1 * c - x2 * s) |
                     ((unsigned)f2bf(x1 * s + x2 * c) << 16);
    *reinterpret_cast<unsigned int*>(Kr + oidx) = o;
  }
}

// ---------------- V transpose: qkv v-part -> VT [B,H,128,T] bf16 ----------------
__global__ __launch_bounds__(256) void k_vtrans(const short* __restrict__ qkv,
                                                short* __restrict__ VT) {
  __shared__ short tile[64][66];
  int bh = blockIdx.x;
  int t0 = blockIdx.y * 64;
  int d0 = blockIdx.z * 64;
  int b = bh >> 4, h = bh & 15;
  int tid = threadIdx.x;
#pragma unroll
  for (int rep = 0; rep < 16; ++rep) {
    int idx = rep * 256 + tid;
    int r = idx >> 6, c = idx & 63;
    tile[r][c] = qkv[(size_t)(b * 2048 + t0 + r) * 6144 + 4096 + h * 128 + d0 + c];
  }
  __syncthreads();
#pragma unroll
  for (int rep = 0; rep < 16; ++rep) {
    int idx = rep * 256 + tid;
    int r = idx >> 6, c = idx & 63;
    VT[(size_t)(bh * 128 + d0 + r) * 2048 + t0 + c] = tile[c][r];
  }
}

// ---------------- causal flash attention (v2) ----------------
// block = (bh, pair): processes q-tiles qt=pair and qt=31-pair sequentially
// -> every block does exactly 33 KV iterations (load-balanced).
// 4 waves x 16 q-rows, KVBLK=64, double-buffered K/V via global_load_lds
// (issue next-tile STAGE before compute, one barrier per tile).
// Row-sum of P via MFMA with all-ones B (no shfl reduce); defer-max (THR=8).
__global__ __launch_bounds__(256) void k_attn(const short* __restrict__ Qr,
                                              const short* __restrict__ Kr,
                                              const short* __restrict__ VT,
                                              short* __restrict__ Y) {
  __shared__ short sK[2][64 * 128];
  __shared__ short sVT[2][128 * 64];
  __shared__ short sP[4][16 * 64];
  const int tid = threadIdx.x, wv = tid >> 6, lane = tid & 63;
  const int l8r = lane >> 3, l8c = lane & 7, l16 = lane & 15, lhi = lane >> 4;
  const int bid = blockIdx.x;
  const int pair = bid & 15, bh = bid >> 4;
  const size_t base = (size_t)bh * 2048 * 128;
  const int b = bh >> 4, h = bh & 15;

  const short ob = (short)0x3F80;                   // bf16 1.0
  const bf16x8 ones = {ob, ob, ob, ob, ob, ob, ob, ob};

  auto stage = [&](int kv0, int buf) {
#pragma unroll
    for (int rr = 0; rr < 4; ++rr) {
      int ch = rr * 4 + wv;
      {                                    // sK: row stride 256B, chunk = 4 rows
        int row = ch * 4 + lhi;
        int wch = l16 ^ (row & 7);         // inverse-swizzled source chunk
        gld_lds16(Kr + base + (size_t)(kv0 + row) * 128 + wch * 8,
                  &sK[buf][ch * 512]);
      }
      {                                    // sVT: row stride 128B, chunk = 8 rows
        int drow = ch * 8 + l8r;
        int wch = l8c ^ (drow & 7);
        gld_lds16(VT + base + (size_t)drow * 2048 + kv0 + wch * 8,
                  &sVT[buf][ch * 512]);
      }
    }
  };

  for (int half = 0; half < 2; ++half) {
    const int qt = half ? 31 - pair : pair;
    const int q0 = qt * 64;
    const int nt = qt + 1;

    bf16x8 qf[4];
    const int qrow = q0 + wv * 16 + l16;
#pragma unroll
    for (int ks = 0; ks < 4; ++ks)
      qf[ks] = *reinterpret_cast<const bf16x8*>(Qr + base + (size_t)qrow * 128 +
                                                ks * 32 + lhi * 8);

    f32x4 acc_o[8] = {};
    f32x4 acc_l = {};
    float m_run[4];
#pragma unroll
    for (int r = 0; r < 4; ++r) m_run[r] = -1e30f;

    stage(0, 0);
    __syncthreads();

    for (int it = 0; it < nt; ++it) {
      const int cur = it & 1;
      if (it + 1 < nt) stage((it + 1) * 64, cur ^ 1);   // prefetch next tile

      // S = Q K^T  (scores already in exp2 domain: kC folded into Q)
      f32x4 sacc[4] = {};
#pragma unroll
      for (int cf = 0; cf < 4; ++cf) {
        int krow = cf * 16 + l16;
#pragma unroll
        for (int ks = 0; ks < 4; ++ks) {
          int e = krow * 128 + ks * 32 + lhi * 8;
          bf16x8 kf = *reinterpret_cast<const bf16x8*>(
              &sK[cur][e ^ ((krow & 7) << 3)]);
          sacc[cf] = __builtin_amdgcn_mfma_f32_16x16x32_bf16(qf[ks], kf,
                                                             sacc[cf], 0, 0, 0);
        }
      }

      if (it == nt - 1) {                  // causal mask on diagonal tile
#pragma unroll
        for (int cf = 0; cf < 4; ++cf) {
          int col = cf * 16 + l16;
#pragma unroll
          for (int r = 0; r < 4; ++r)
            if (col > wv * 16 + lhi * 4 + r) sacc[cf][r] = -3e38f;
        }
      }

      // defer-max: slow path only when a row max grows past THR=8 (exp2-units)
      bool exceed = false;
#pragma unroll
      for (int cf = 0; cf < 4; ++cf)
#pragma unroll
        for (int r = 0; r < 4; ++r)
          exceed |= (sacc[cf][r] > m_run[r] + 8.f);

      if (__any(exceed)) {
        float resc[4];
#pragma unroll
        for (int r = 0; r < 4; ++r) {
          float mx = fmaxf(fmaxf(sacc[0][r], sacc[1][r]),
                           fmaxf(sacc[2][r], sacc[3][r]));
          mx = fmaxf(mx, __shfl_xor(mx, 1));
          mx = fmaxf(mx, __shfl_xor(mx, 2));
          mx = fmaxf(mx, __shfl_xor(mx, 4));
          mx = fmaxf(mx, __shfl_xor(mx, 8));
          float mnew = fmaxf(m_run[r], mx);
          resc[r] = exp2f(m_run[r] - mnew);
          m_run[r] = mnew;
        }
#pragma unroll
        for (int df = 0; df < 8; ++df)
#pragma unroll
          for (int r = 0; r < 4; ++r) acc_o[df][r] *= resc[r];
#pragma unroll
        for (int r = 0; r < 4; ++r) acc_l[r] *= resc[r];
      }

      // P = exp2(S - m), bf16, into per-wave swizzled LDS (A-frag reshape)
#pragma unroll
      for (int cf = 0; cf < 4; ++cf)
#pragma unroll
        for (int r = 0; r < 4; ++r) {
          float p = exp2f(sacc[cf][r] - m_run[r]);
          int prow = lhi * 4 + r;
          int e = prow * 64 + cf * 16 + l16;
          sP[wv][e ^ ((prow & 7) << 3)] = (short)f2bf(p);
        }

      // O += P V ; l += P * ones  (row-sum via MFMA, no shuffle reduce)
#pragma unroll
      for (int kk = 0; kk < 2; ++kk) {
        int e = l16 * 64 + kk * 32 + lhi * 8;
        bf16x8 pa = *reinterpret_cast<const bf16x8*>(
            &sP[wv][e ^ ((l16 & 7) << 3)]);
        acc_l = __builtin_amdgcn_mfma_f32_16x16x32_bf16(pa, ones, acc_l, 0, 0, 0);
#pragma unroll
        for (int df = 0; df < 8; ++df) {
          int vrow = df * 16 + l16;
          int ev = vrow * 64 + kk * 32 + lhi * 8;
          bf16x8 vb = *reinterpret_cast<const bf16x8*>(
              &sVT[cur][ev ^ ((vrow & 7) << 3)]);
          acc_o[df] = __builtin_amdgcn_mfma_f32_16x16x32_bf16(pa, vb,
                                                              acc_o[df], 0, 0, 0);
        }
      }
      __syncthreads();   // drains prefetch vmcnt + protects LDS buffers
    }

    float inv[4];
#pragma unroll
    for (int r = 0; r < 4; ++r) inv[r] = 1.f / acc_l[r];
#pragma unroll
    for (int df = 0; df < 8; ++df) {
      int col = h * 128 + df * 16 + l16;
#pragma unroll
      for (int r = 0; r < 4; ++r) {
        int row = q0 + wv * 16 + lhi * 4 + r;
        Y[((size_t)b * 2048 + row) * 2048 + col] =
            (short)f2bf(acc_o[df][r] * inv[r]);
      }
    }
  }
}

// ---------------- launch ----------------
extern "C" void kernel_launch(void* const* d_in, const int* in_sizes, int n_in,
                              void* d_out, int out_size, void* d_ws, size_t ws_size,
                              hipStream_t stream) {
  const float* x        = (const float*)d_in[0];
  const float* w_attn   = (const float*)d_in[1];
  const float* w_proj   = (const float*)d_in[2];
  const float* rope_cos = (const float*)d_in[3];
  const float* rope_sin = (const float*)d_in[4];

  char* ws = (char*)d_ws;                     // 256 MiB total layout
  short* xbf    = (short*)(ws);               // 33.5 MB  [8192][2048]
  short* wattnT = (short*)(ws + 33554432ull); // 25.2 MB  [6144][2048]
  short* wprojT = (short*)(ws + 58720256ull); //  8.4 MB  [2048][2048]
  short* qkv    = (short*)(ws + 67108864ull); // 100.7 MB [8192][6144]
  short* Y      = qkv;                        // alias dead q-region (33.5 MB)
  short* Qr     = (short*)(ws + 167772160ull);// 33.5 MB  [B,H,T,128]
  short* Kr     = (short*)(ws + 201326592ull);// 33.5 MB  [B,H,T,128]
  short* VT     = (short*)(ws + 234881024ull);// 33.5 MB  [B,H,128,T]

  k_conv<<<16384, 256, 0, stream>>>(x, xbf, 4194304);
  k_transpose<<<3072, 256, 0, stream>>>(w_attn, wattnT, 2048, 6144);
  k_transpose<<<1024, 256, 0, stream>>>(w_proj, wprojT, 2048, 2048);
  k_gemm_bt<short><<<dim3(64, 48), 256, 0, stream>>>(xbf, wattnT, qkv,
                                                     8192, 6144, 2048);
  k_rope<<<32768, 256, 0, stream>>>(qkv, rope_cos, rope_sin, Qr, Kr);
  k_vtrans<<<dim3(64, 32, 2), 256, 0, stream>>>(qkv, VT);
  k_attn<<<1024, 256, 0, stream>>>(Qr, Kr, VT, Y);
  k_gemm_bt<float><<<dim3(64, 16), 256, 0, stream>>>(Y, wprojT, (float*)d_out,
                                                     8192, 2048, 2048);
}

// Round 3
// 514.204 us; speedup vs baseline: 1.6158x; 1.2501x over previous
//
#include <hip/hip_runtime.h>
#include <cstdint>
#include <cstddef>

#define DEVI __device__ __forceinline__

typedef __attribute__((ext_vector_type(8))) short bf16x8;
typedef __attribute__((ext_vector_type(4))) float f32x4;

DEVI unsigned short f2bf(float f) {
  unsigned int u = __float_as_uint(f);
  u += 0x7fffu + ((u >> 16) & 1u);   // RNE
  return (unsigned short)(u >> 16);
}
DEVI float bf2f(unsigned int us) { return __uint_as_float(us << 16); }

DEVI void gld_lds16(const void* g, void* l) {
  __builtin_amdgcn_global_load_lds(
      (const __attribute__((address_space(1))) void*)g,
      (__attribute__((address_space(3))) void*)l, 16, 0, 0);
}

// ---------------- fp32 -> bf16 elementwise ----------------
__global__ __launch_bounds__(256) void k_conv(const float* __restrict__ in,
                                              short* __restrict__ out, int n4) {
  int i = blockIdx.x * 256 + threadIdx.x;
  if (i >= n4) return;
  float4 v = reinterpret_cast<const float4*>(in)[i];
  uint2 o;
  o.x = (unsigned)f2bf(v.x) | ((unsigned)f2bf(v.y) << 16);
  o.y = (unsigned)f2bf(v.z) | ((unsigned)f2bf(v.w) << 16);
  reinterpret_cast<uint2*>(out)[i] = o;
}

// ---------------- fp32 [R][C] -> bf16 [C][R] transpose ----------------
__global__ __launch_bounds__(256) void k_transpose(const float* __restrict__ in,
                                                   short* __restrict__ out,
                                                   int R, int Cc) {
  __shared__ short tile[64][66];
  int tcols = Cc >> 6;
  int tb = blockIdx.x % tcols;
  int rb = blockIdx.x / tcols;
  int tid = threadIdx.x;
#pragma unroll
  for (int rep = 0; rep < 16; ++rep) {
    int idx = rep * 256 + tid;
    int r = idx >> 6, c = idx & 63;
    tile[r][c] = (short)f2bf(in[(size_t)(rb * 64 + r) * Cc + tb * 64 + c]);
  }
  __syncthreads();
#pragma unroll
  for (int rep = 0; rep < 16; ++rep) {
    int idx = rep * 256 + tid;
    int r = idx >> 6, c = idx & 63;
    out[(size_t)(tb * 64 + r) * R + rb * 64 + c] = tile[c][r];
  }
}

// ---------------- bf16 GEMM, B^T input: 8-phase-class pipelined ----------------
// C[M][N] = A[M][K] * BT[N][K]^T.  BM=BN=256, BK=32, 512 thr (8 waves 2Mx4N),
// 4 LDS buffers (128KB), staging runs 2 K-tiles ahead (provably race-free:
// target buffer's readers retired 2 tiles ago behind barriers), counted
// vmcnt(4) once per tile (never 0 in loop). Granule-XOR LDS swizzle
// (g' = g ^ ((row>>1)&3)) applied on the global source + swizzled ds_read.
template <typename OutT>
__global__ __launch_bounds__(512, 2) void k_gemm8(const short* __restrict__ A,
                                                  const short* __restrict__ BT,
                                                  OutT* __restrict__ C,
                                                  int M, int N, int K) {
  __shared__ short sA[4][8192];   // [buf][256 rows][32 k], swizzled granules
  __shared__ short sB[4][8192];
  const int tid = threadIdx.x;
  const int wv = tid >> 6, lane = tid & 63;
  const int l16 = lane & 15, lhi = lane >> 4;
  const int wr = wv >> 2, wc = wv & 3;          // wave grid 2M x 4N
  const int bm = blockIdx.x * 256, bn = blockIdx.y * 256;

  const int srow0 = wv * 16 + (lane >> 2);      // staging row within 128-half
  const int sgs = lane & 3;                     // stored granule

  auto stageA = [&](int kt, int b) {
#pragma unroll
    for (int j = 0; j < 2; ++j) {
      int row = j * 128 + srow0;
      int g = sgs ^ ((row >> 1) & 3);           // logical granule for this slot
      gld_lds16(A + (size_t)(bm + row) * K + kt + g * 8,
                &sA[b][j * 4096 + wv * 512]);   // wave-uniform base + lane*16B
    }
  };
  auto stageB = [&](int kt, int b) {
#pragma unroll
    for (int j = 0; j < 2; ++j) {
      int row = j * 128 + srow0;
      int g = sgs ^ ((row >> 1) & 3);
      gld_lds16(BT + (size_t)(bn + row) * K + kt + g * 8,
                &sB[b][j * 4096 + wv * 512]);
    }
  };

  f32x4 acc[8][4] = {};
  const int NT = K >> 5;

  stageA(0, 0); stageB(0, 0);
  stageA(32, 1); stageB(32, 1);
  asm volatile("s_waitcnt vmcnt(4)" ::: "memory");   // tile 0 landed
  __builtin_amdgcn_s_barrier();
  asm volatile("" ::: "memory");

  for (int t = 0; t < NT; ++t) {
    const int cur = t & 3;
    const int nb = (t + 2) & 3;
    bf16x8 bfr[4], af[4];
    // ---- phase 0: B frags (all n) + A frags m=0..3 ----
#pragma unroll
    for (int n = 0; n < 4; ++n) {
      int row = wc * 64 + n * 16 + l16;
      bfr[n] = *(const bf16x8*)&sB[cur][row * 32 + (lhi ^ ((row >> 1) & 3)) * 8];
    }
#pragma unroll
    for (int m = 0; m < 4; ++m) {
      int row = wr * 128 + m * 16 + l16;
      af[m] = *(const bf16x8*)&sA[cur][row * 32 + (lhi ^ ((row >> 1) & 3)) * 8];
    }
    if (t + 2 < NT) stageA((t + 2) * 32, nb);
    __builtin_amdgcn_s_barrier();
    asm volatile("s_waitcnt lgkmcnt(0)" ::: "memory");
    __builtin_amdgcn_s_setprio(1);
#pragma unroll
    for (int m = 0; m < 4; ++m)
#pragma unroll
      for (int n = 0; n < 4; ++n)
        acc[m][n] = __builtin_amdgcn_mfma_f32_16x16x32_bf16(af[m], bfr[n],
                                                            acc[m][n], 0, 0, 0);
    __builtin_amdgcn_s_setprio(0);
    __builtin_amdgcn_s_barrier();
    asm volatile("" ::: "memory");
    // ---- phase 1: A frags m=4..7 (B reused) ----
#pragma unroll
    for (int m = 0; m < 4; ++m) {
      int row = wr * 128 + 64 + m * 16 + l16;
      af[m] = *(const bf16x8*)&sA[cur][row * 32 + (lhi ^ ((row >> 1) & 3)) * 8];
    }
    if (t + 2 < NT) {
      stageB((t + 2) * 32, nb);
      asm volatile("s_waitcnt vmcnt(4)" ::: "memory");  // tile t+1 fully landed
    } else if (t + 1 < NT) {
      asm volatile("s_waitcnt vmcnt(0)" ::: "memory");  // epilogue drain
    }
    __builtin_amdgcn_s_barrier();
    asm volatile("s_waitcnt lgkmcnt(0)" ::: "memory");
    __builtin_amdgcn_s_setprio(1);
#pragma unroll
    for (int m = 0; m < 4; ++m)
#pragma unroll
      for (int n = 0; n < 4; ++n)
        acc[m + 4][n] = __builtin_amdgcn_mfma_f32_16x16x32_bf16(af[m], bfr[n],
                                                                acc[m + 4][n],
                                                                0, 0, 0);
    __builtin_amdgcn_s_setprio(0);
    __builtin_amdgcn_s_barrier();
    asm volatile("" ::: "memory");
  }

#pragma unroll
  for (int m = 0; m < 8; ++m) {
#pragma unroll
    for (int n = 0; n < 4; ++n) {
      int col = bn + wc * 64 + n * 16 + l16;
#pragma unroll
      for (int r = 0; r < 4; ++r) {
        int row = bm + wr * 128 + m * 16 + lhi * 4 + r;
        if constexpr (sizeof(OutT) == 2)
          C[(size_t)row * N + col] = (OutT)f2bf(acc[m][n][r]);
        else
          C[(size_t)row * N + col] = acc[m][n][r];
      }
    }
  }
}

// ---------------- RoPE: qkv -> Qr,Kr in [B,H,T,128] bf16 ----------------
// Q additionally pre-scaled by 1/sqrt(hd) * log2(e) so QK^T lands in exp2 domain.
__global__ __launch_bounds__(256) void k_rope(const short* __restrict__ qkv,
                                              const float* __restrict__ cosb,
                                              const float* __restrict__ sinb,
                                              short* __restrict__ Qr,
                                              short* __restrict__ Kr) {
  const float kC = 0.08838834764831845f * 1.44269504088896340f;
  int gid = blockIdx.x * 4 + (threadIdx.x >> 6);  // (b*T+t)*H + h
  int lane = threadIdx.x & 63;                    // pair index 0..63
  int h = gid & 15;
  int bt = gid >> 4;
  int t = bt & 2047;
  int b = bt >> 11;
  float c = cosb[t * 64 + lane];
  float s = sinb[t * 64 + lane];
  size_t qidx = (size_t)bt * 6144 + h * 128 + 2 * lane;
  size_t oidx = ((size_t)(b * 16 + h) * 2048 + t) * 128 + 2 * lane;
  unsigned int qp = *reinterpret_cast<const unsigned int*>(qkv + qidx);
  {
    float x1 = bf2f(qp & 0xffffu), x2 = bf2f(qp >> 16);
    unsigned int o = (unsigned)f2bf((x1 * c - x2 * s) * kC) |
                     ((unsigned)f2bf((x1 * s + x2 * c) * kC) << 16);
    *reinterpret_cast<unsigned int*>(Qr + oidx) = o;
  }
  unsigned int kp = *reinterpret_cast<const unsigned int*>(qkv + qidx + 2048);
  {
    float x1 = bf2f(kp & 0xffffu), x2 = bf2f(kp >> 16);
    unsigned int o = (unsigned)f2bf(x1 * c - x2 * s) |
                     ((unsigned)f2bf(x1 * s + x2 * c) << 16);
    *reinterpret_cast<unsigned int*>(Kr + oidx) = o;
  }
}

// ---------------- V transpose: qkv v-part -> VT [B,H,128,T] bf16 ----------------
__global__ __launch_bounds__(256) void k_vtrans(const short* __restrict__ qkv,
                                                short* __restrict__ VT) {
  __shared__ short tile[64][66];
  int bh = blockIdx.x;
  int t0 = blockIdx.y * 64;
  int d0 = blockIdx.z * 64;
  int b = bh >> 4, h = bh & 15;
  int tid = threadIdx.x;
#pragma unroll
  for (int rep = 0; rep < 16; ++rep) {
    int idx = rep * 256 + tid;
    int r = idx >> 6, c = idx & 63;
    tile[r][c] = qkv[(size_t)(b * 2048 + t0 + r) * 6144 + 4096 + h * 128 + d0 + c];
  }
  __syncthreads();
#pragma unroll
  for (int rep = 0; rep < 16; ++rep) {
    int idx = rep * 256 + tid;
    int r = idx >> 6, c = idx & 63;
    VT[(size_t)(bh * 128 + d0 + r) * 2048 + t0 + c] = tile[c][r];
  }
}

// ---------------- causal flash attention (v2) ----------------
__global__ __launch_bounds__(256) void k_attn(const short* __restrict__ Qr,
                                              const short* __restrict__ Kr,
                                              const short* __restrict__ VT,
                                              short* __restrict__ Y) {
  __shared__ short sK[2][64 * 128];
  __shared__ short sVT[2][128 * 64];
  __shared__ short sP[4][16 * 64];
  const int tid = threadIdx.x, wv = tid >> 6, lane = tid & 63;
  const int l8r = lane >> 3, l8c = lane & 7, l16 = lane & 15, lhi = lane >> 4;
  const int bid = blockIdx.x;
  const int pair = bid & 15, bh = bid >> 4;
  const size_t base = (size_t)bh * 2048 * 128;
  const int b = bh >> 4, h = bh & 15;

  const short ob = (short)0x3F80;                   // bf16 1.0
  const bf16x8 ones = {ob, ob, ob, ob, ob, ob, ob, ob};

  auto stage = [&](int kv0, int buf) {
#pragma unroll
    for (int rr = 0; rr < 4; ++rr) {
      int ch = rr * 4 + wv;
      {                                    // sK: row stride 256B, chunk = 4 rows
        int row = ch * 4 + lhi;
        int wch = l16 ^ (row & 7);         // inverse-swizzled source chunk
        gld_lds16(Kr + base + (size_t)(kv0 + row) * 128 + wch * 8,
                  &sK[buf][ch * 512]);
      }
      {                                    // sVT: row stride 128B, chunk = 8 rows
        int drow = ch * 8 + l8r;
        int wch = l8c ^ (drow & 7);
        gld_lds16(VT + base + (size_t)drow * 2048 + kv0 + wch * 8,
                  &sVT[buf][ch * 512]);
      }
    }
  };

  for (int half = 0; half < 2; ++half) {
    const int qt = half ? 31 - pair : pair;
    const int q0 = qt * 64;
    const int nt = qt + 1;

    bf16x8 qf[4];
    const int qrow = q0 + wv * 16 + l16;
#pragma unroll
    for (int ks = 0; ks < 4; ++ks)
      qf[ks] = *reinterpret_cast<const bf16x8*>(Qr + base + (size_t)qrow * 128 +
                                                ks * 32 + lhi * 8);

    f32x4 acc_o[8] = {};
    f32x4 acc_l = {};
    float m_run[4];
#pragma unroll
    for (int r = 0; r < 4; ++r) m_run[r] = -1e30f;

    stage(0, 0);
    __syncthreads();

    for (int it = 0; it < nt; ++it) {
      const int cur = it & 1;
      if (it + 1 < nt) stage((it + 1) * 64, cur ^ 1);   // prefetch next tile

      // S = Q K^T  (scores already in exp2 domain: kC folded into Q)
      f32x4 sacc[4] = {};
#pragma unroll
      for (int cf = 0; cf < 4; ++cf) {
        int krow = cf * 16 + l16;
#pragma unroll
        for (int ks = 0; ks < 4; ++ks) {
          int e = krow * 128 + ks * 32 + lhi * 8;
          bf16x8 kf = *reinterpret_cast<const bf16x8*>(
              &sK[cur][e ^ ((krow & 7) << 3)]);
          sacc[cf] = __builtin_amdgcn_mfma_f32_16x16x32_bf16(qf[ks], kf,
                                                             sacc[cf], 0, 0, 0);
        }
      }

      if (it == nt - 1) {                  // causal mask on diagonal tile
#pragma unroll
        for (int cf = 0; cf < 4; ++cf) {
          int col = cf * 16 + l16;
#pragma unroll
          for (int r = 0; r < 4; ++r)
            if (col > wv * 16 + lhi * 4 + r) sacc[cf][r] = -3e38f;
        }
      }

      // defer-max: slow path only when a row max grows past THR=8 (exp2-units)
      bool exceed = false;
#pragma unroll
      for (int cf = 0; cf < 4; ++cf)
#pragma unroll
        for (int r = 0; r < 4; ++r)
          exceed |= (sacc[cf][r] > m_run[r] + 8.f);

      if (__any(exceed)) {
        float resc[4];
#pragma unroll
        for (int r = 0; r < 4; ++r) {
          float mx = fmaxf(fmaxf(sacc[0][r], sacc[1][r]),
                           fmaxf(sacc[2][r], sacc[3][r]));
          mx = fmaxf(mx, __shfl_xor(mx, 1));
          mx = fmaxf(mx, __shfl_xor(mx, 2));
          mx = fmaxf(mx, __shfl_xor(mx, 4));
          mx = fmaxf(mx, __shfl_xor(mx, 8));
          float mnew = fmaxf(m_run[r], mx);
          resc[r] = exp2f(m_run[r] - mnew);
          m_run[r] = mnew;
        }
#pragma unroll
        for (int df = 0; df < 8; ++df)
#pragma unroll
          for (int r = 0; r < 4; ++r) acc_o[df][r] *= resc[r];
#pragma unroll
        for (int r = 0; r < 4; ++r) acc_l[r] *= resc[r];
      }

      // P = exp2(S - m), bf16, into per-wave swizzled LDS (A-frag reshape)
#pragma unroll
      for (int cf = 0; cf < 4; ++cf)
#pragma unroll
        for (int r = 0; r < 4; ++r) {
          float p = exp2f(sacc[cf][r] - m_run[r]);
          int prow = lhi * 4 + r;
          int e = prow * 64 + cf * 16 + l16;
          sP[wv][e ^ ((prow & 7) << 3)] = (short)f2bf(p);
        }

      // O += P V ; l += P * ones  (row-sum via MFMA, no shuffle reduce)
#pragma unroll
      for (int kk = 0; kk < 2; ++kk) {
        int e = l16 * 64 + kk * 32 + lhi * 8;
        bf16x8 pa = *reinterpret_cast<const bf16x8*>(
            &sP[wv][e ^ ((l16 & 7) << 3)]);
        acc_l = __builtin_amdgcn_mfma_f32_16x16x32_bf16(pa, ones, acc_l, 0, 0, 0);
#pragma unroll
        for (int df = 0; df < 8; ++df) {
          int vrow = df * 16 + l16;
          int ev = vrow * 64 + kk * 32 + lhi * 8;
          bf16x8 vb = *reinterpret_cast<const bf16x8*>(
              &sVT[cur][ev ^ ((vrow & 7) << 3)]);
          acc_o[df] = __builtin_amdgcn_mfma_f32_16x16x32_bf16(pa, vb,
                                                              acc_o[df], 0, 0, 0);
        }
      }
      __syncthreads();   // drains prefetch vmcnt + protects LDS buffers
    }

    float inv[4];
#pragma unroll
    for (int r = 0; r < 4; ++r) inv[r] = 1.f / acc_l[r];
#pragma unroll
    for (int df = 0; df < 8; ++df) {
      int col = h * 128 + df * 16 + l16;
#pragma unroll
      for (int r = 0; r < 4; ++r) {
        int row = q0 + wv * 16 + lhi * 4 + r;
        Y[((size_t)b * 2048 + row) * 2048 + col] =
            (short)f2bf(acc_o[df][r] * inv[r]);
      }
    }
  }
}

// ---------------- launch ----------------
extern "C" void kernel_launch(void* const* d_in, const int* in_sizes, int n_in,
                              void* d_out, int out_size, void* d_ws, size_t ws_size,
                              hipStream_t stream) {
  const float* x        = (const float*)d_in[0];
  const float* w_attn   = (const float*)d_in[1];
  const float* w_proj   = (const float*)d_in[2];
  const float* rope_cos = (const float*)d_in[3];
  const float* rope_sin = (const float*)d_in[4];

  char* ws = (char*)d_ws;                     // 256 MiB total layout
  short* xbf    = (short*)(ws);               // 33.5 MB  [8192][2048]
  short* wattnT = (short*)(ws + 33554432ull); // 25.2 MB  [6144][2048]
  short* wprojT = (short*)(ws + 58720256ull); //  8.4 MB  [2048][2048]
  short* qkv    = (short*)(ws + 67108864ull); // 100.7 MB [8192][6144]
  short* Y      = qkv;                        // alias dead q-region (33.5 MB)
  short* Qr     = (short*)(ws + 167772160ull);// 33.5 MB  [B,H,T,128]
  short* Kr     = (short*)(ws + 201326592ull);// 33.5 MB  [B,H,T,128]
  short* VT     = (short*)(ws + 234881024ull);// 33.5 MB  [B,H,128,T]

  k_conv<<<16384, 256, 0, stream>>>(x, xbf, 4194304);
  k_transpose<<<3072, 256, 0, stream>>>(w_attn, wattnT, 2048, 6144);
  k_transpose<<<1024, 256, 0, stream>>>(w_proj, wprojT, 2048, 2048);
  k_gemm8<short><<<dim3(32, 24), 512, 0, stream>>>(xbf, wattnT, qkv,
                                                   8192, 6144, 2048);
  k_rope<<<32768, 256, 0, stream>>>(qkv, rope_cos, rope_sin, Qr, Kr);
  k_vtrans<<<dim3(64, 32, 2), 256, 0, stream>>>(qkv, VT);
  k_attn<<<1024, 256, 0, stream>>>(Qr, Kr, VT, Y);
  k_gemm8<float><<<dim3(32, 8), 512, 0, stream>>>(Y, wprojT, (float*)d_out,
                                                  8192, 2048, 2048);
}

// Round 4
// 496.026 us; speedup vs baseline: 1.6750x; 1.0366x over previous
//
#include <hip/hip_runtime.h>
#include <cstdint>
#include <cstddef>

#define DEVI __device__ __forceinline__

typedef __attribute__((ext_vector_type(8))) short bf16x8;
typedef __attribute__((ext_vector_type(4))) float f32x4;

DEVI unsigned short f2bf(float f) {
  unsigned int u = __float_as_uint(f);
  u += 0x7fffu + ((u >> 16) & 1u);   // RNE
  return (unsigned short)(u >> 16);
}
DEVI float bf2f(unsigned int us) { return __uint_as_float(us << 16); }

DEVI void gld_lds16(const void* g, void* l) {
  __builtin_amdgcn_global_load_lds(
      (const __attribute__((address_space(1))) void*)g,
      (__attribute__((address_space(3))) void*)l, 16, 0, 0);
}

// ---------------- fp32 -> bf16 elementwise ----------------
__global__ __launch_bounds__(256) void k_conv(const float* __restrict__ in,
                                              short* __restrict__ out, int n4) {
  int i = blockIdx.x * 256 + threadIdx.x;
  if (i >= n4) return;
  float4 v = reinterpret_cast<const float4*>(in)[i];
  uint2 o;
  o.x = (unsigned)f2bf(v.x) | ((unsigned)f2bf(v.y) << 16);
  o.y = (unsigned)f2bf(v.z) | ((unsigned)f2bf(v.w) << 16);
  reinterpret_cast<uint2*>(out)[i] = o;
}

// ---------------- fp32 [R][C] -> bf16 [C][R] transpose ----------------
__global__ __launch_bounds__(256) void k_transpose(const float* __restrict__ in,
                                                   short* __restrict__ out,
                                                   int R, int Cc) {
  __shared__ short tile[64][66];
  int tcols = Cc >> 6;
  int tb = blockIdx.x % tcols;
  int rb = blockIdx.x / tcols;
  int tid = threadIdx.x;
#pragma unroll
  for (int rep = 0; rep < 16; ++rep) {
    int idx = rep * 256 + tid;
    int r = idx >> 6, c = idx & 63;
    tile[r][c] = (short)f2bf(in[(size_t)(rb * 64 + r) * Cc + tb * 64 + c]);
  }
  __syncthreads();
#pragma unroll
  for (int rep = 0; rep < 16; ++rep) {
    int idx = rep * 256 + tid;
    int r = idx >> 6, c = idx & 63;
    out[(size_t)(tb * 64 + r) * R + rb * 64 + c] = tile[c][r];
  }
}

// ---------------- bf16 GEMM, B^T input: pipelined, 1 barrier per K-tile ----
// BM=BN=256, BK=32, 512 thr (8 waves 2Mx4N), 4 LDS buffers (128KB).
// Staging runs 3 K-tiles ahead (race-free: buffer (t+3)&3's readers retired
// at tile t-2 behind barriers). One counted vmcnt(4) + one s_barrier per
// tile. Register frag DOUBLE-BUFFER: tile t+1's 12 ds_read_b128 issue before
// tile t's 32-MFMA cluster -> LDS latency/BW hides under MFMA.
template <typename OutT>
__global__ __launch_bounds__(512, 2) void k_gemm8(const short* __restrict__ A,
                                                  const short* __restrict__ BT,
                                                  OutT* __restrict__ C,
                                                  int M, int N, int K) {
  __shared__ short sA[4][8192];   // [buf][256 rows][32 k], swizzled granules
  __shared__ short sB[4][8192];
  const int tid = threadIdx.x;
  const int wv = tid >> 6, lane = tid & 63;
  const int l16 = lane & 15, lhi = lane >> 4;
  const int wr = wv >> 2, wc = wv & 3;          // wave grid 2M x 4N
  const int bm = blockIdx.x * 256, bn = blockIdx.y * 256;
  const int srow0 = wv * 16 + (lane >> 2);      // staging row within 128-half
  const int sgs = lane & 3;                     // stored granule
  const int NT = K >> 5;

  auto stageA = [&](int kt, int b) {
#pragma unroll
    for (int j = 0; j < 2; ++j) {
      int row = j * 128 + srow0;
      int g = sgs ^ ((row >> 1) & 3);           // logical granule for this slot
      gld_lds16(A + (size_t)(bm + row) * K + kt + g * 8,
                &sA[b][j * 4096 + wv * 512]);   // wave-uniform base + lane*16B
    }
  };
  auto stageB = [&](int kt, int b) {
#pragma unroll
    for (int j = 0; j < 2; ++j) {
      int row = j * 128 + srow0;
      int g = sgs ^ ((row >> 1) & 3);
      gld_lds16(BT + (size_t)(bn + row) * K + kt + g * 8,
                &sB[b][j * 4096 + wv * 512]);
    }
  };

  f32x4 acc[8][4] = {};
  bf16x8 aP[8], bP[4], aQ[8], bQ[4];

#define FRAG_READ(DA, DB, BUF)                                                 \
  {                                                                            \
    const short* bufA_ = sA[(BUF)];                                            \
    const short* bufB_ = sB[(BUF)];                                            \
    _Pragma("unroll") for (int n = 0; n < 4; ++n) {                            \
      int row = wc * 64 + n * 16 + l16;                                        \
      DB[n] = *(const bf16x8*)&bufB_[row * 32 + ((lhi ^ ((row >> 1) & 3)) << 3)]; \
    }                                                                          \
    _Pragma("unroll") for (int m = 0; m < 8; ++m) {                            \
      int row = wr * 128 + m * 16 + l16;                                       \
      DA[m] = *(const bf16x8*)&bufA_[row * 32 + ((lhi ^ ((row >> 1) & 3)) << 3)]; \
    }                                                                          \
  }

#define TILE_BODY(T, CA, CB, NA, NB)                                           \
  {                                                                            \
    const int t_ = (T);                                                        \
    if (t_ + 1 < NT) FRAG_READ(NA, NB, (t_ + 1) & 3);                          \
    if (t_ + 3 < NT) {                                                         \
      stageA((t_ + 3) * 32, (t_ + 3) & 3);                                     \
      stageB((t_ + 3) * 32, (t_ + 3) & 3);                                     \
    }                                                                          \
    __builtin_amdgcn_sched_barrier(0);                                         \
    if (t_ + 3 < NT) {                                                         \
      asm volatile("s_waitcnt vmcnt(4)" ::: "memory");                         \
    } else {                                                                   \
      asm volatile("s_waitcnt vmcnt(0)" ::: "memory");                         \
    }                                                                          \
    __builtin_amdgcn_sched_barrier(0);                                         \
    __builtin_amdgcn_s_setprio(1);                                             \
    _Pragma("unroll") for (int m = 0; m < 8; ++m)                              \
        _Pragma("unroll") for (int n = 0; n < 4; ++n)                          \
            acc[m][n] = __builtin_amdgcn_mfma_f32_16x16x32_bf16(               \
                CA[m], CB[n], acc[m][n], 0, 0, 0);                             \
    __builtin_amdgcn_s_setprio(0);                                             \
    __builtin_amdgcn_sched_barrier(0);                                         \
    __builtin_amdgcn_s_barrier();                                              \
    __builtin_amdgcn_sched_barrier(0);                                         \
  }

  // prologue: stage tiles 0,1,2; publish 0 and 1; preload tile-0 frags
  stageA(0, 0); stageB(0, 0);
  stageA(32, 1); stageB(32, 1);
  stageA(64, 2); stageB(64, 2);
  asm volatile("s_waitcnt vmcnt(8)" ::: "memory");   // tile 0 landed
  __builtin_amdgcn_s_barrier();
  FRAG_READ(aP, bP, 0);
  asm volatile("s_waitcnt vmcnt(4)" ::: "memory");   // tile 1 landed
  __builtin_amdgcn_s_barrier();
  __builtin_amdgcn_sched_barrier(0);

  for (int t = 0; t < NT; t += 2) {      // NT even (K % 64 == 0)
    TILE_BODY(t, aP, bP, aQ, bQ);
    TILE_BODY(t + 1, aQ, bQ, aP, bP);
  }
#undef FRAG_READ
#undef TILE_BODY

#pragma unroll
  for (int m = 0; m < 8; ++m) {
#pragma unroll
    for (int n = 0; n < 4; ++n) {
      int col = bn + wc * 64 + n * 16 + l16;
#pragma unroll
      for (int r = 0; r < 4; ++r) {
        int row = bm + wr * 128 + m * 16 + lhi * 4 + r;
        if constexpr (sizeof(OutT) == 2)
          C[(size_t)row * N + col] = (OutT)f2bf(acc[m][n][r]);
        else
          C[(size_t)row * N + col] = acc[m][n][r];
      }
    }
  }
}

// ---------------- RoPE: qkv -> Qr,Kr in [B,H,T,128] bf16 ----------------
// Q additionally pre-scaled by 1/sqrt(hd) * log2(e) so QK^T lands in exp2 domain.
__global__ __launch_bounds__(256) void k_rope(const short* __restrict__ qkv,
                                              const float* __restrict__ cosb,
                                              const float* __restrict__ sinb,
                                              short* __restrict__ Qr,
                                              short* __restrict__ Kr) {
  const float kC = 0.08838834764831845f * 1.44269504088896340f;
  int gid = blockIdx.x * 4 + (threadIdx.x >> 6);  // (b*T+t)*H + h
  int lane = threadIdx.x & 63;                    // pair index 0..63
  int h = gid & 15;
  int bt = gid >> 4;
  int t = bt & 2047;
  int b = bt >> 11;
  float c = cosb[t * 64 + lane];
  float s = sinb[t * 64 + lane];
  size_t qidx = (size_t)bt * 6144 + h * 128 + 2 * lane;
  size_t oidx = ((size_t)(b * 16 + h) * 2048 + t) * 128 + 2 * lane;
  unsigned int qp = *reinterpret_cast<const unsigned int*>(qkv + qidx);
  {
    float x1 = bf2f(qp & 0xffffu), x2 = bf2f(qp >> 16);
    unsigned int o = (unsigned)f2bf((x1 * c - x2 * s) * kC) |
                     ((unsigned)f2bf((x1 * s + x2 * c) * kC) << 16);
    *reinterpret_cast<unsigned int*>(Qr + oidx) = o;
  }
  unsigned int kp = *reinterpret_cast<const unsigned int*>(qkv + qidx + 2048);
  {
    float x1 = bf2f(kp & 0xffffu), x2 = bf2f(kp >> 16);
    unsigned int o = (unsigned)f2bf(x1 * c - x2 * s) |
                     ((unsigned)f2bf(x1 * s + x2 * c) << 16);
    *reinterpret_cast<unsigned int*>(Kr + oidx) = o;
  }
}

// ---------------- V transpose: qkv v-part -> VT [B,H,128,T] bf16 ----------------
__global__ __launch_bounds__(256) void k_vtrans(const short* __restrict__ qkv,
                                                short* __restrict__ VT) {
  __shared__ short tile[64][66];
  int bh = blockIdx.x;
  int t0 = blockIdx.y * 64;
  int d0 = blockIdx.z * 64;
  int b = bh >> 4, h = bh & 15;
  int tid = threadIdx.x;
#pragma unroll
  for (int rep = 0; rep < 16; ++rep) {
    int idx = rep * 256 + tid;
    int r = idx >> 6, c = idx & 63;
    tile[r][c] = qkv[(size_t)(b * 2048 + t0 + r) * 6144 + 4096 + h * 128 + d0 + c];
  }
  __syncthreads();
#pragma unroll
  for (int rep = 0; rep < 16; ++rep) {
    int idx = rep * 256 + tid;
    int r = idx >> 6, c = idx & 63;
    VT[(size_t)(bh * 128 + d0 + r) * 2048 + t0 + c] = tile[c][r];
  }
}

// ---------------- causal flash attention (v2) ----------------
__global__ __launch_bounds__(256) void k_attn(const short* __restrict__ Qr,
                                              const short* __restrict__ Kr,
                                              const short* __restrict__ VT,
                                              short* __restrict__ Y) {
  __shared__ short sK[2][64 * 128];
  __shared__ short sVT[2][128 * 64];
  __shared__ short sP[4][16 * 64];
  const int tid = threadIdx.x, wv = tid >> 6, lane = tid & 63;
  const int l8r = lane >> 3, l8c = lane & 7, l16 = lane & 15, lhi = lane >> 4;
  const int bid = blockIdx.x;
  const int pair = bid & 15, bh = bid >> 4;
  const size_t base = (size_t)bh * 2048 * 128;
  const int b = bh >> 4, h = bh & 15;

  const short ob = (short)0x3F80;                   // bf16 1.0
  const bf16x8 ones = {ob, ob, ob, ob, ob, ob, ob, ob};

  auto stage = [&](int kv0, int buf) {
#pragma unroll
    for (int rr = 0; rr < 4; ++rr) {
      int ch = rr * 4 + wv;
      {                                    // sK: row stride 256B, chunk = 4 rows
        int row = ch * 4 + lhi;
        int wch = l16 ^ (row & 7);         // inverse-swizzled source chunk
        gld_lds16(Kr + base + (size_t)(kv0 + row) * 128 + wch * 8,
                  &sK[buf][ch * 512]);
      }
      {                                    // sVT: row stride 128B, chunk = 8 rows
        int drow = ch * 8 + l8r;
        int wch = l8c ^ (drow & 7);
        gld_lds16(VT + base + (size_t)drow * 2048 + kv0 + wch * 8,
                  &sVT[buf][ch * 512]);
      }
    }
  };

  for (int half = 0; half < 2; ++half) {
    const int qt = half ? 31 - pair : pair;
    const int q0 = qt * 64;
    const int nt = qt + 1;

    bf16x8 qf[4];
    const int qrow = q0 + wv * 16 + l16;
#pragma unroll
    for (int ks = 0; ks < 4; ++ks)
      qf[ks] = *reinterpret_cast<const bf16x8*>(Qr + base + (size_t)qrow * 128 +
                                                ks * 32 + lhi * 8);

    f32x4 acc_o[8] = {};
    f32x4 acc_l = {};
    float m_run[4];
#pragma unroll
    for (int r = 0; r < 4; ++r) m_run[r] = -1e30f;

    stage(0, 0);
    __syncthreads();

    for (int it = 0; it < nt; ++it) {
      const int cur = it & 1;
      if (it + 1 < nt) stage((it + 1) * 64, cur ^ 1);   // prefetch next tile

      // S = Q K^T  (scores already in exp2 domain: kC folded into Q)
      f32x4 sacc[4] = {};
#pragma unroll
      for (int cf = 0; cf < 4; ++cf) {
        int krow = cf * 16 + l16;
#pragma unroll
        for (int ks = 0; ks < 4; ++ks) {
          int e = krow * 128 + ks * 32 + lhi * 8;
          bf16x8 kf = *reinterpret_cast<const bf16x8*>(
              &sK[cur][e ^ ((krow & 7) << 3)]);
          sacc[cf] = __builtin_amdgcn_mfma_f32_16x16x32_bf16(qf[ks], kf,
                                                             sacc[cf], 0, 0, 0);
        }
      }

      if (it == nt - 1) {                  // causal mask on diagonal tile
#pragma unroll
        for (int cf = 0; cf < 4; ++cf) {
          int col = cf * 16 + l16;
#pragma unroll
          for (int r = 0; r < 4; ++r)
            if (col > wv * 16 + lhi * 4 + r) sacc[cf][r] = -3e38f;
        }
      }

      // defer-max: slow path only when a row max grows past THR=8 (exp2-units)
      bool exceed = false;
#pragma unroll
      for (int cf = 0; cf < 4; ++cf)
#pragma unroll
        for (int r = 0; r < 4; ++r)
          exceed |= (sacc[cf][r] > m_run[r] + 8.f);

      if (__any(exceed)) {
        float resc[4];
#pragma unroll
        for (int r = 0; r < 4; ++r) {
          float mx = fmaxf(fmaxf(sacc[0][r], sacc[1][r]),
                           fmaxf(sacc[2][r], sacc[3][r]));
          mx = fmaxf(mx, __shfl_xor(mx, 1));
          mx = fmaxf(mx, __shfl_xor(mx, 2));
          mx = fmaxf(mx, __shfl_xor(mx, 4));
          mx = fmaxf(mx, __shfl_xor(mx, 8));
          float mnew = fmaxf(m_run[r], mx);
          resc[r] = exp2f(m_run[r] - mnew);
          m_run[r] = mnew;
        }
#pragma unroll
        for (int df = 0; df < 8; ++df)
#pragma unroll
          for (int r = 0; r < 4; ++r) acc_o[df][r] *= resc[r];
#pragma unroll
        for (int r = 0; r < 4; ++r) acc_l[r] *= resc[r];
      }

      // P = exp2(S - m), bf16, into per-wave swizzled LDS (A-frag reshape)
#pragma unroll
      for (int cf = 0; cf < 4; ++cf)
#pragma unroll
        for (int r = 0; r < 4; ++r) {
          float p = exp2f(sacc[cf][r] - m_run[r]);
          int prow = lhi * 4 + r;
          int e = prow * 64 + cf * 16 + l16;
          sP[wv][e ^ ((prow & 7) << 3)] = (short)f2bf(p);
        }

      // O += P V ; l += P * ones  (row-sum via MFMA, no shuffle reduce)
#pragma unroll
      for (int kk = 0; kk < 2; ++kk) {
        int e = l16 * 64 + kk * 32 + lhi * 8;
        bf16x8 pa = *reinterpret_cast<const bf16x8*>(
            &sP[wv][e ^ ((l16 & 7) << 3)]);
        acc_l = __builtin_amdgcn_mfma_f32_16x16x32_bf16(pa, ones, acc_l, 0, 0, 0);
#pragma unroll
        for (int df = 0; df < 8; ++df) {
          int vrow = df * 16 + l16;
          int ev = vrow * 64 + kk * 32 + lhi * 8;
          bf16x8 vb = *reinterpret_cast<const bf16x8*>(
              &sVT[cur][ev ^ ((vrow & 7) << 3)]);
          acc_o[df] = __builtin_amdgcn_mfma_f32_16x16x32_bf16(pa, vb,
                                                              acc_o[df], 0, 0, 0);
        }
      }
      __syncthreads();   // drains prefetch vmcnt + protects LDS buffers
    }

    float inv[4];
#pragma unroll
    for (int r = 0; r < 4; ++r) inv[r] = 1.f / acc_l[r];
#pragma unroll
    for (int df = 0; df < 8; ++df) {
      int col = h * 128 + df * 16 + l16;
#pragma unroll
      for (int r = 0; r < 4; ++r) {
        int row = q0 + wv * 16 + lhi * 4 + r;
        Y[((size_t)b * 2048 + row) * 2048 + col] =
            (short)f2bf(acc_o[df][r] * inv[r]);
      }
    }
  }
}

// ---------------- launch ----------------
extern "C" void kernel_launch(void* const* d_in, const int* in_sizes, int n_in,
                              void* d_out, int out_size, void* d_ws, size_t ws_size,
                              hipStream_t stream) {
  const float* x        = (const float*)d_in[0];
  const float* w_attn   = (const float*)d_in[1];
  const float* w_proj   = (const float*)d_in[2];
  const float* rope_cos = (const float*)d_in[3];
  const float* rope_sin = (const float*)d_in[4];

  char* ws = (char*)d_ws;                     // 256 MiB total layout
  short* xbf    = (short*)(ws);               // 33.5 MB  [8192][2048]
  short* wattnT = (short*)(ws + 33554432ull); // 25.2 MB  [6144][2048]
  short* wprojT = (short*)(ws + 58720256ull); //  8.4 MB  [2048][2048]
  short* qkv    = (short*)(ws + 67108864ull); // 100.7 MB [8192][6144]
  short* Y      = qkv;                        // alias dead q-region (33.5 MB)
  short* Qr     = (short*)(ws + 167772160ull);// 33.5 MB  [B,H,T,128]
  short* Kr     = (short*)(ws + 201326592ull);// 33.5 MB  [B,H,T,128]
  short* VT     = (short*)(ws + 234881024ull);// 33.5 MB  [B,H,128,T]

  k_conv<<<16384, 256, 0, stream>>>(x, xbf, 4194304);
  k_transpose<<<3072, 256, 0, stream>>>(w_attn, wattnT, 2048, 6144);
  k_transpose<<<1024, 256, 0, stream>>>(w_proj, wprojT, 2048, 2048);
  k_gemm8<short><<<dim3(32, 24), 512, 0, stream>>>(xbf, wattnT, qkv,
                                                   8192, 6144, 2048);
  k_rope<<<32768, 256, 0, stream>>>(qkv, rope_cos, rope_sin, Qr, Kr);
  k_vtrans<<<dim3(64, 32, 2), 256, 0, stream>>>(qkv, VT);
  k_attn<<<1024, 256, 0, stream>>>(Qr, Kr, VT, Y);
  k_gemm8<float><<<dim3(32, 8), 512, 0, stream>>>(Y, wprojT, (float*)d_out,
                                                  8192, 2048, 2048);
}